// Round 5
// baseline (768.726 us; speedup 1.0000x reference)
//
#include <hip/hip_runtime.h>
#include <math.h>

// GCN 2-layer: out = A_norm @ relu(A_norm @ x @ W1 + b1) @ W2 + b2
// A_norm = D_dst^{-1/2} (A + I) D_src^{-1/2}
// Structure:
//   - Degree histograms via LDS privatization (no global atomics).
//   - Fused reduce: partial-sum -> cnt_dst, out_isqrt, in_isqrt, local scan.
//   - CSR fill (returning int atomics), then gather-based aggregation.
//   - Gather is XCD-SLICED: blockIdx%8 selects a 16-float feature slice; with
//     round-robin block->XCD dispatch each XCD keeps its 3.2MB slice L2-resident
//     (round-4 profile: gathers were L2-miss bound, 189MB fetch @3.6TB/s).
//   - GEMMs: split-bf16 MFMA (Dekker hi/lo, 3 products), W pre-packed.

constexpr int IN_DIM  = 128;
constexpr int HID_DIM = 256;
constexpr int OUT_DIM = 128;

constexpr int HALF_BINS = 25600;          // node-range half (25600*2 >= N), % 1024 == 0
constexpr int HWORDS    = HALF_BINS / 2;  // packed ushort words
constexpr int HIST_G    = 64;             // blocks per (array, half)

#define DIV_UP(a, b) (((a) + (b) - 1) / (b))

typedef __attribute__((ext_vector_type(8))) short bf16x8;
typedef __attribute__((ext_vector_type(4))) float f32x4;

// ---- privatized degree histogram: grid (HIST_G, 4); y = half*2 + arr ----
__global__ __launch_bounds__(256) void k_hist(const int* __restrict__ ei, int E,
                                              unsigned* __restrict__ partials) {
    __shared__ unsigned h32[HWORDS];  // 51200 B, packed 2x ushort
    const int tid = threadIdx.x;
    const int g = blockIdx.x;
    const int arr = blockIdx.y & 1, half = blockIdx.y >> 1;
    const int lo = half * HALF_BINS;
    const int* edges = ei + (size_t)arr * E;

    for (int i = tid; i < HWORDS; i += 256) h32[i] = 0;
    __syncthreads();

    const int chunk = DIV_UP(E, HIST_G);
    const int beg = g * chunk;
    const int end = min(beg + chunk, E);
    if ((beg & 3) == 0) {
        for (int base = beg + tid * 4; base < end; base += 256 * 4) {
            if (base + 3 < end) {
                int4 v = *reinterpret_cast<const int4*>(edges + base);
                int r;
                r = v.x - lo; if ((unsigned)r < HALF_BINS) atomicAdd(&h32[r >> 1], 1u << ((r & 1) << 4));
                r = v.y - lo; if ((unsigned)r < HALF_BINS) atomicAdd(&h32[r >> 1], 1u << ((r & 1) << 4));
                r = v.z - lo; if ((unsigned)r < HALF_BINS) atomicAdd(&h32[r >> 1], 1u << ((r & 1) << 4));
                r = v.w - lo; if ((unsigned)r < HALF_BINS) atomicAdd(&h32[r >> 1], 1u << ((r & 1) << 4));
            } else {
                for (int k = base; k < end; ++k) {
                    int r = edges[k] - lo;
                    if ((unsigned)r < HALF_BINS) atomicAdd(&h32[r >> 1], 1u << ((r & 1) << 4));
                }
            }
        }
    } else {
        for (int k = beg + tid; k < end; k += 256) {
            int r = edges[k] - lo;
            if ((unsigned)r < HALF_BINS) atomicAdd(&h32[r >> 1], 1u << ((r & 1) << 4));
        }
    }
    __syncthreads();

    unsigned* outp = partials + (size_t)(blockIdx.y * HIST_G + g) * HWORDS;
    for (int i = tid; i < HWORDS; i += 256) outp[i] = h32[i];
}

// ---- fused reduce + normalizers + local scan. Block b: nodes [b*1024,(b+1)*1024) ----
__global__ __launch_bounds__(256) void k_reduce_scan(
    const unsigned* __restrict__ partials,
    int* __restrict__ cnt_dst, float* __restrict__ out_isqrt, float* __restrict__ in_isqrt,
    int* __restrict__ scan_loc, int* __restrict__ chunk_sum, int n) {
    __shared__ int wsum[4];
    const int tid = threadIdx.x, lane = tid & 63, wid = tid >> 6;
    const int bnode = blockIdx.x * 1024;
    const int half = (bnode >= HALF_BINS) ? 1 : 0;  // HALF_BINS % 1024 == 0, no straddle
    const int w0 = ((bnode - half * HALF_BINS) >> 1) + tid * 2;

    const unsigned* ps = partials + (size_t)(2 * half + 0) * HIST_G * HWORDS;
    const unsigned* pd = partials + (size_t)(2 * half + 1) * HIST_G * HWORDS;

    int s0 = 0, s1 = 0, s2 = 0, s3 = 0;
    int d0 = 0, d1 = 0, d2 = 0, d3 = 0;
#pragma unroll 4
    for (int g = 0; g < HIST_G; ++g) {
        unsigned a = ps[(size_t)g * HWORDS + w0];
        unsigned b = ps[(size_t)g * HWORDS + w0 + 1];
        unsigned c = pd[(size_t)g * HWORDS + w0];
        unsigned d = pd[(size_t)g * HWORDS + w0 + 1];
        s0 += a & 0xFFFF; s1 += a >> 16; s2 += b & 0xFFFF; s3 += b >> 16;
        d0 += c & 0xFFFF; d1 += c >> 16; d2 += d & 0xFFFF; d3 += d >> 16;
    }

    const int n0 = bnode + tid * 4;
    int sc[4] = {s0, s1, s2, s3};
    int dc[4] = {d0, d1, d2, d3};
#pragma unroll
    for (int j = 0; j < 4; ++j) {
        int node = n0 + j;
        if (node < n) {
            cnt_dst[node] = dc[j];
            out_isqrt[node] = rsqrtf((float)(sc[j] + 1));
            in_isqrt[node]  = rsqrtf((float)(dc[j] + 1));
        } else {
            dc[j] = 0;
        }
    }

    // local exclusive scan of dc over the block's 1024 values
    int s = dc[0] + dc[1] + dc[2] + dc[3];
    int x = s;
#pragma unroll
    for (int off = 1; off < 64; off <<= 1) { int t = __shfl_up(x, off); if (lane >= off) x += t; }
    if (lane == 63) wsum[wid] = x;
    __syncthreads();
    int wo = 0;
    for (int w = 0; w < wid; ++w) wo += wsum[w];
    int excl = wo + x - s;
    int run = excl;
#pragma unroll
    for (int j = 0; j < 4; ++j) {
        int node = n0 + j;
        if (node < n) scan_loc[node] = run;
        run += dc[j];
    }
    if (tid == 255) chunk_sum[blockIdx.x] = wo + x;
}

__global__ void k_scan_chunks(int* __restrict__ chunk_sums, int nc) {  // nc <= 64
    int l = threadIdx.x;
    int v = (l < nc) ? chunk_sums[l] : 0;
    int x = v;
#pragma unroll
    for (int off = 1; off < 64; off <<= 1) { int t = __shfl_up(x, off); if (l >= off) x += t; }
    if (l < nc) chunk_sums[l] = x - v;
}

__global__ void k_scan_apply(const int* __restrict__ local, const int* __restrict__ chunk_sums,
                             int* __restrict__ row_off, int* __restrict__ cursor, int n) {
    int i = (blockIdx.x * blockDim.x + threadIdx.x) * 4;
    if (i >= n) return;
    int add = chunk_sums[i >> 10];
    if (i + 3 < n) {
        int4 v = *reinterpret_cast<const int4*>(local + i);
        v.x += add; v.y += add; v.z += add; v.w += add;
        *reinterpret_cast<int4*>(row_off + i) = v;
        *reinterpret_cast<int4*>(cursor + i) = v;
    } else {
        for (int k = i; k < n; ++k) { int t = local[k] + add; row_off[k] = t; cursor[k] = t; }
    }
}

__global__ void k_fill_csr4(const int* __restrict__ src, const int* __restrict__ dst,
                            int* __restrict__ cursor, int* __restrict__ csr_src, int e) {
    int i = (blockIdx.x * blockDim.x + threadIdx.x) * 4;
    if (i + 3 < e) {
        int4 s = *reinterpret_cast<const int4*>(src + i);
        int4 d = *reinterpret_cast<const int4*>(dst + i);
        int p0 = atomicAdd(&cursor[d.x], 1);
        int p1 = atomicAdd(&cursor[d.y], 1);
        int p2 = atomicAdd(&cursor[d.z], 1);
        int p3 = atomicAdd(&cursor[d.w], 1);
        csr_src[p0] = s.x; csr_src[p1] = s.y; csr_src[p2] = s.z; csr_src[p3] = s.w;
    } else {
        for (int k = i; k < e; ++k) { int p = atomicAdd(&cursor[dst[k]], 1); csr_src[p] = src[k]; }
    }
}

// XCD-sliced gather. blockIdx.x & 7 = slice (16 floats = 64B of the 128-d row);
// with round-robin block->XCD dispatch each XCD streams one 3.2MB slice from L2.
// Wave per node: lane = g*16 + c; 4 edge-groups x 16 dims; shfl_xor reduce.
// layer1 (HAS_SCALE):  out[node][col] = sum_{u in N(node)+self} feat[u][col]*scale[u]
// layer2 (HAS_OUT):    out[node][col] = oscale[node]*(sum feat[u][col]) + bias[col]
template <bool HAS_SCALE, bool HAS_OUT>
__global__ __launch_bounds__(256) void k_gather_slice(
    const float* __restrict__ feat, const int* __restrict__ row_off,
    const int* __restrict__ cnt, const int* __restrict__ csr_src,
    const float* __restrict__ scale, const float* __restrict__ oscale,
    const float* __restrict__ bias, float* __restrict__ outv, int n) {
    const int slice = blockIdx.x & 7;
    const int nblk  = blockIdx.x >> 3;
    const int wave = threadIdx.x >> 6;
    const int lane = threadIdx.x & 63;
    const int g = lane >> 4, c = lane & 15;
    const int node = nblk * 4 + wave;
    if (node >= n) return;
    const int col = slice * 16 + c;
    const float* fcol = feat + col;

    float acc = 0.f;
    const int b = row_off[node];
    const int e2 = b + cnt[node];
    for (int k = b + g; k < e2; k += 4) {
        int s = __builtin_nontemporal_load(csr_src + k);
        float v = fcol[(size_t)s * 128];
        acc += HAS_SCALE ? v * scale[s] : v;
    }
    if (g == 0) {  // self loop
        float v = fcol[(size_t)node * 128];
        acc += HAS_SCALE ? v * scale[node] : v;
    }
    acc += __shfl_xor(acc, 16);
    acc += __shfl_xor(acc, 32);
    if (g == 0) {
        if (HAS_OUT) acc = acc * oscale[node] + bias[col];
        __builtin_nontemporal_store(acc, outv + (size_t)node * 128 + col);
    }
}

// Pack both W's fp32 -> hi/lo bf16 in MFMA-B fragment order (one dispatch).
// idx = ((nt*KT + kt)*64 + lane)*8 + j ; k = kt*32 + (lane>>4)*8 + j ; col = nt*16 + (lane&15)
__device__ __forceinline__ void pack_one(const float* __restrict__ W, short* __restrict__ hi,
                                         short* __restrict__ lo, int idx, int KT, int N) {
    int j = idx & 7;
    int l = (idx >> 3) & 63;
    int rest = idx >> 9;
    int kt = rest % KT;
    int nt = rest / KT;
    int k = kt * 32 + ((l >> 4) << 3) + j;
    int col = nt * 16 + (l & 15);
    float w = W[(size_t)k * N + col];
    unsigned u = __builtin_bit_cast(unsigned, w);
    hi[idx] = (short)(u >> 16);
    float hif = __builtin_bit_cast(float, u & 0xFFFF0000u);
    lo[idx] = (short)(__builtin_bit_cast(unsigned, w - hif) >> 16);
}

__global__ void k_pack_both(const float* __restrict__ W1, const float* __restrict__ W2,
                            short* __restrict__ h1, short* __restrict__ l1,
                            short* __restrict__ h2, short* __restrict__ l2) {
    int idx = blockIdx.x * blockDim.x + threadIdx.x;
    const int T1 = IN_DIM * HID_DIM;
    const int T2 = HID_DIM * OUT_DIM;
    if (idx < T1) pack_one(W1, h1, l1, idx, IN_DIM / 32, HID_DIM);
    else if (idx < T1 + T2) pack_one(W2, h2, l2, idx - T1, HID_DIM / 32, OUT_DIM);
}

// C[M x Nc] = epi( (rs_in ⊙ A[M x K]) @ W ), split-bf16 MFMA (hi*hi + lo*hi + hi*lo).
// Block: 256 thr = 4 waves; wave: 16 rows x 128 cols (8 col-tiles of 16x16x32).
template <int KT, bool HAS_RSIN, bool HAS_BIAS, bool RELU, bool HAS_RSOUT>
__global__ __launch_bounds__(256) void k_gemm_mfma(
    const float* __restrict__ A, const short* __restrict__ Bp_hi,
    const short* __restrict__ Bp_lo, const float* __restrict__ bias,
    const float* __restrict__ rs_in, const float* __restrict__ rs_out,
    float* __restrict__ C, int M, int Nc) {
    const int K = KT * 32;
    const int lane = threadIdx.x & 63;
    const int wave = threadIdx.x >> 6;
    const int row0 = blockIdx.y * 64 + wave * 16;
    const int colt0 = blockIdx.x * 8;

    int arow = row0 + (lane & 15);
    int ar = arow < M ? arow : M - 1;
    const int koff = (lane >> 4) << 3;
    const float rs = HAS_RSIN ? rs_in[ar] : 1.0f;

    f32x4 acc[8];
#pragma unroll
    for (int t = 0; t < 8; ++t) acc[t] = (f32x4){0.f, 0.f, 0.f, 0.f};

    const bf16x8* bh = reinterpret_cast<const bf16x8*>(Bp_hi);
    const bf16x8* bl = reinterpret_cast<const bf16x8*>(Bp_lo);

#pragma unroll
    for (int kt = 0; kt < KT; ++kt) {
        const float* ap = A + (size_t)ar * K + kt * 32 + koff;
        float av[8];
        *reinterpret_cast<float4*>(&av[0]) = *reinterpret_cast<const float4*>(ap);
        *reinterpret_cast<float4*>(&av[4]) = *reinterpret_cast<const float4*>(ap + 4);
        bf16x8 a_hi, a_lo;
#pragma unroll
        for (int j = 0; j < 8; ++j) {
            float a = av[j] * rs;
            unsigned u = __builtin_bit_cast(unsigned, a);
            a_hi[j] = (short)(u >> 16);
            float hif = __builtin_bit_cast(float, u & 0xFFFF0000u);
            a_lo[j] = (short)(__builtin_bit_cast(unsigned, a - hif) >> 16);
        }
#pragma unroll
        for (int ct = 0; ct < 8; ++ct) {
            int bidx = (colt0 + ct) * KT + kt;
            bf16x8 bhv = bh[bidx * 64 + lane];
            bf16x8 blv = bl[bidx * 64 + lane];
            acc[ct] = __builtin_amdgcn_mfma_f32_16x16x32_bf16(a_hi, bhv, acc[ct], 0, 0, 0);
            acc[ct] = __builtin_amdgcn_mfma_f32_16x16x32_bf16(a_lo, bhv, acc[ct], 0, 0, 0);
            acc[ct] = __builtin_amdgcn_mfma_f32_16x16x32_bf16(a_hi, blv, acc[ct], 0, 0, 0);
        }
    }

    const int crow0 = row0 + ((lane >> 4) << 2);
    float rso[4];
#pragma unroll
    for (int j = 0; j < 4; ++j)
        rso[j] = HAS_RSOUT ? ((crow0 + j < M) ? rs_out[crow0 + j] : 0.f) : 1.0f;

#pragma unroll
    for (int ct = 0; ct < 8; ++ct) {
        int col = (colt0 + ct) * 16 + (lane & 15);
        float bv = HAS_BIAS ? bias[col] : 0.f;
#pragma unroll
        for (int j = 0; j < 4; ++j) {
            int row = crow0 + j;
            if (row >= M) continue;
            float v = acc[ct][j] + bv;
            if (RELU) v = fmaxf(v, 0.f);
            v *= rso[j];
            C[(size_t)row * Nc + col] = v;
        }
    }
}

extern "C" void kernel_launch(void* const* d_in, const int* in_sizes, int n_in,
                              void* d_out, int out_size, void* d_ws, size_t ws_size,
                              hipStream_t stream) {
    const float* x  = (const float*)d_in[0];
    const int*   ei = (const int*)d_in[1];
    const float* W1 = (const float*)d_in[2];
    const float* b1 = (const float*)d_in[3];
    const float* W2 = (const float*)d_in[4];
    const float* b2 = (const float*)d_in[5];
    float* out = (float*)d_out;

    const int N = in_sizes[0] / IN_DIM;
    const int E = in_sizes[1] / 2;
    const int* src = ei;
    const int* dst = ei + E;

    char* ws = (char*)d_ws;
    size_t off = 0;
    auto alloc = [&](size_t bytes) {
        void* p = ws + off;
        off += (bytes + 255) & ~(size_t)255;
        return p;
    };
    int*   cnt_dst   = (int*)alloc((size_t)N * sizeof(int));
    float* out_isqrt = (float*)alloc((size_t)N * sizeof(float));
    float* in_isqrt  = (float*)alloc((size_t)N * sizeof(float));
    int*   row_off   = (int*)alloc((size_t)N * sizeof(int));
    int*   cursor    = (int*)alloc((size_t)N * sizeof(int));
    int*   scan_loc  = (int*)alloc((size_t)N * sizeof(int));
    int*   chunk_sum = (int*)alloc(64 * sizeof(int));
    int*   csr_src   = (int*)alloc((size_t)E * sizeof(int));
    short* W1p_hi    = (short*)alloc((size_t)IN_DIM * HID_DIM * sizeof(short));
    short* W1p_lo    = (short*)alloc((size_t)IN_DIM * HID_DIM * sizeof(short));
    short* W2p_hi    = (short*)alloc((size_t)HID_DIM * OUT_DIM * sizeof(short));
    short* W2p_lo    = (short*)alloc((size_t)HID_DIM * OUT_DIM * sizeof(short));
    float* m1 = (float*)alloc((size_t)N * IN_DIM * sizeof(float));
    float* h1 = (float*)alloc((size_t)N * HID_DIM * sizeof(float));
    float* t2 = (float*)alloc((size_t)N * OUT_DIM * sizeof(float));

    // partials (13.1 MB) overlay m1: dead before k_gather_slice writes m1.
    unsigned* partials = (unsigned*)m1;

    const int thr = 256;
    const int nchunks = DIV_UP(N, 1024);  // 49
    const int gather_grid = 8 * DIV_UP(N, 4);  // slice-major: blockIdx%8 = slice -> XCD

    // degrees + normalizers + CSR (no global atomics for counting)
    k_hist<<<dim3(HIST_G, 4), 256, 0, stream>>>(ei, E, partials);
    k_reduce_scan<<<nchunks, 256, 0, stream>>>(partials, cnt_dst, out_isqrt, in_isqrt,
                                               scan_loc, chunk_sum, N);
    k_scan_chunks<<<1, 64, 0, stream>>>(chunk_sum, nchunks);
    k_scan_apply<<<DIV_UP(N, 4 * thr), thr, 0, stream>>>(scan_loc, chunk_sum, row_off, cursor, N);
    k_fill_csr4<<<DIV_UP(E / 4, thr), thr, 0, stream>>>(src, dst, cursor, csr_src, E);

    // weight packing (fragment-ordered bf16 hi/lo), one dispatch
    k_pack_both<<<DIV_UP(IN_DIM * HID_DIM + HID_DIM * OUT_DIM, thr), thr, 0, stream>>>(
        W1, W2, W1p_hi, W1p_lo, W2p_hi, W2p_lo);

    // layer 1: m1 = (A+I)(out_isqrt ⊙ x); h1 = relu((in_isqrt ⊙ m1)@W1 + b1)
    k_gather_slice<true, false><<<gather_grid, 256, 0, stream>>>(
        x, row_off, cnt_dst, csr_src, out_isqrt, nullptr, nullptr, m1, N);
    k_gemm_mfma<IN_DIM / 32, true, true, true, false>
        <<<dim3(HID_DIM / 128, DIV_UP(N, 64)), 256, 0, stream>>>(
            m1, W1p_hi, W1p_lo, b1, in_isqrt, nullptr, h1, N, HID_DIM);

    // layer 2: t2 = (h1@W2) ⊙ out_isqrt; out = in_isqrt ⊙ ((A+I) t2) + b2
    k_gemm_mfma<HID_DIM / 32, false, false, false, true>
        <<<dim3(OUT_DIM / 128, DIV_UP(N, 64)), 256, 0, stream>>>(
            h1, W2p_hi, W2p_lo, nullptr, nullptr, out_isqrt, t2, N, OUT_DIM);
    k_gather_slice<false, true><<<gather_grid, 256, 0, stream>>>(
        t2, row_off, cnt_dst, csr_src, nullptr, in_isqrt, b2, out, N);
}

// Round 6
// 314.992 us; speedup vs baseline: 2.4405x; 2.4405x over previous
//
#include <hip/hip_runtime.h>
#include <math.h>

// GCN 2-layer: out = A_norm @ relu(A_norm @ x @ W1 + b1) @ W2 + b2
// A_norm = D_dst^{-1/2} (A + I) D_src^{-1/2}
// Structure:
//   - Degree histograms via LDS privatization (no global atomics).
//   - Fused reduce: partial sums -> cnt_dst/isqrts/local scan + per-histblock
//     exclusive prefix (for atomic-free CSR fill).
//   - k_fill_rank: CSR fill with LDS-only ranking (pos = row_off + prefix + rank).
//   - Gather: wave/node, half-wave float4 row loads, 8 rows in flight.
//     (round-5 XCD slicing REVERTED: 128B line granularity x 50k nodes = 6.4MB
//      per-XCD footprint > 4MB L2 -> no residency; 61 -> 286us regression.)
//   - GEMMs: split-bf16 MFMA (Dekker hi/lo, 3 products), W pre-packed.

constexpr int IN_DIM  = 128;
constexpr int HID_DIM = 256;
constexpr int OUT_DIM = 128;

constexpr int HALF_BINS = 25600;          // node-range half (25600*2 >= N), % 1024 == 0
constexpr int HWORDS    = HALF_BINS / 2;  // packed ushort words
constexpr int HIST_G    = 64;             // blocks per (array, half)

#define DIV_UP(a, b) (((a) + (b) - 1) / (b))

typedef __attribute__((ext_vector_type(8))) short bf16x8;
typedef __attribute__((ext_vector_type(4))) float f32x4;

// ---- privatized degree histogram: grid (HIST_G, 4); y = half*2 + arr ----
__global__ __launch_bounds__(256) void k_hist(const int* __restrict__ ei, int E,
                                              unsigned* __restrict__ partials) {
    __shared__ unsigned h32[HWORDS];  // 51200 B, packed 2x ushort
    const int tid = threadIdx.x;
    const int g = blockIdx.x;
    const int arr = blockIdx.y & 1, half = blockIdx.y >> 1;
    const int lo = half * HALF_BINS;
    const int* edges = ei + (size_t)arr * E;

    for (int i = tid; i < HWORDS; i += 256) h32[i] = 0;
    __syncthreads();

    const int chunk = DIV_UP(E, HIST_G);
    const int beg = g * chunk;
    const int end = min(beg + chunk, E);
    if ((beg & 3) == 0) {
        for (int base = beg + tid * 4; base < end; base += 256 * 4) {
            if (base + 3 < end) {
                int4 v = *reinterpret_cast<const int4*>(edges + base);
                int r;
                r = v.x - lo; if ((unsigned)r < HALF_BINS) atomicAdd(&h32[r >> 1], 1u << ((r & 1) << 4));
                r = v.y - lo; if ((unsigned)r < HALF_BINS) atomicAdd(&h32[r >> 1], 1u << ((r & 1) << 4));
                r = v.z - lo; if ((unsigned)r < HALF_BINS) atomicAdd(&h32[r >> 1], 1u << ((r & 1) << 4));
                r = v.w - lo; if ((unsigned)r < HALF_BINS) atomicAdd(&h32[r >> 1], 1u << ((r & 1) << 4));
            } else {
                for (int k = base; k < end; ++k) {
                    int r = edges[k] - lo;
                    if ((unsigned)r < HALF_BINS) atomicAdd(&h32[r >> 1], 1u << ((r & 1) << 4));
                }
            }
        }
    } else {
        for (int k = beg + tid; k < end; k += 256) {
            int r = edges[k] - lo;
            if ((unsigned)r < HALF_BINS) atomicAdd(&h32[r >> 1], 1u << ((r & 1) << 4));
        }
    }
    __syncthreads();

    unsigned* outp = partials + (size_t)(blockIdx.y * HIST_G + g) * HWORDS;
    for (int i = tid; i < HWORDS; i += 256) outp[i] = h32[i];
}

// ---- fused reduce + normalizers + local scan + per-g dst prefix ----
// Block b: nodes [b*1024,(b+1)*1024). prefix layout: [half][g][HWORDS] packed ushort.
__global__ __launch_bounds__(256) void k_reduce_scan(
    const unsigned* __restrict__ partials,
    int* __restrict__ cnt_dst, float* __restrict__ out_isqrt, float* __restrict__ in_isqrt,
    int* __restrict__ scan_loc, int* __restrict__ chunk_sum,
    unsigned* __restrict__ prefix, int n) {
    __shared__ int wsum[4];
    const int tid = threadIdx.x, lane = tid & 63, wid = tid >> 6;
    const int bnode = blockIdx.x * 1024;
    const int half = (bnode >= HALF_BINS) ? 1 : 0;  // HALF_BINS % 1024 == 0, no straddle
    const int w0 = ((bnode - half * HALF_BINS) >> 1) + tid * 2;

    const unsigned* ps = partials + (size_t)(2 * half + 0) * HIST_G * HWORDS;
    const unsigned* pd = partials + (size_t)(2 * half + 1) * HIST_G * HWORDS;
    unsigned* pgp = prefix + (size_t)half * HIST_G * HWORDS;

    int s0 = 0, s1 = 0, s2 = 0, s3 = 0;
    int d0 = 0, d1 = 0, d2 = 0, d3 = 0;
#pragma unroll 4
    for (int g = 0; g < HIST_G; ++g) {
        unsigned a = ps[(size_t)g * HWORDS + w0];
        unsigned b = ps[(size_t)g * HWORDS + w0 + 1];
        unsigned c = pd[(size_t)g * HWORDS + w0];
        unsigned d = pd[(size_t)g * HWORDS + w0 + 1];
        // exclusive prefix over g (before accumulating this g's counts)
        pgp[(size_t)g * HWORDS + w0]     = (unsigned)(d0 & 0xFFFF) | ((unsigned)(d1 & 0xFFFF) << 16);
        pgp[(size_t)g * HWORDS + w0 + 1] = (unsigned)(d2 & 0xFFFF) | ((unsigned)(d3 & 0xFFFF) << 16);
        s0 += a & 0xFFFF; s1 += a >> 16; s2 += b & 0xFFFF; s3 += b >> 16;
        d0 += c & 0xFFFF; d1 += c >> 16; d2 += d & 0xFFFF; d3 += d >> 16;
    }

    const int n0 = bnode + tid * 4;
    int sc[4] = {s0, s1, s2, s3};
    int dc[4] = {d0, d1, d2, d3};
#pragma unroll
    for (int j = 0; j < 4; ++j) {
        int node = n0 + j;
        if (node < n) {
            cnt_dst[node] = dc[j];
            out_isqrt[node] = rsqrtf((float)(sc[j] + 1));
            in_isqrt[node]  = rsqrtf((float)(dc[j] + 1));
        } else {
            dc[j] = 0;
        }
    }

    // local exclusive scan of dc over the block's 1024 values
    int s = dc[0] + dc[1] + dc[2] + dc[3];
    int x = s;
#pragma unroll
    for (int off = 1; off < 64; off <<= 1) { int t = __shfl_up(x, off); if (lane >= off) x += t; }
    if (lane == 63) wsum[wid] = x;
    __syncthreads();
    int wo = 0;
    for (int w = 0; w < wid; ++w) wo += wsum[w];
    int excl = wo + x - s;
    int run = excl;
#pragma unroll
    for (int j = 0; j < 4; ++j) {
        int node = n0 + j;
        if (node < n) scan_loc[node] = run;
        run += dc[j];
    }
    if (tid == 255) chunk_sum[blockIdx.x] = wo + x;
}

__global__ void k_scan_chunks(int* __restrict__ chunk_sums, int nc) {  // nc <= 64
    int l = threadIdx.x;
    int v = (l < nc) ? chunk_sums[l] : 0;
    int x = v;
#pragma unroll
    for (int off = 1; off < 64; off <<= 1) { int t = __shfl_up(x, off); if (l >= off) x += t; }
    if (l < nc) chunk_sums[l] = x - v;
}

__global__ void k_scan_apply(const int* __restrict__ local, const int* __restrict__ chunk_sums,
                             int* __restrict__ row_off, int n) {
    int i = (blockIdx.x * blockDim.x + threadIdx.x) * 4;
    if (i >= n) return;
    int add = chunk_sums[i >> 10];
    if (i + 3 < n) {
        int4 v = *reinterpret_cast<const int4*>(local + i);
        v.x += add; v.y += add; v.z += add; v.w += add;
        *reinterpret_cast<int4*>(row_off + i) = v;
    } else {
        for (int k = i; k < n; ++k) row_off[k] = local[k] + add;
    }
}

// ---- atomic-free CSR fill: LDS rank + per-g prefix. grid (HIST_G, 2). ----
__global__ __launch_bounds__(256) void k_fill_rank(
    const int* __restrict__ src, const int* __restrict__ dst,
    const int* __restrict__ row_off, const unsigned* __restrict__ prefix,
    int* __restrict__ csr_src, int E) {
    __shared__ unsigned rk[HWORDS];  // 51.2 KB
    const int tid = threadIdx.x;
    const int g = blockIdx.x, half = blockIdx.y;
    const int lo = half * HALF_BINS;
    for (int i = tid; i < HWORDS; i += 256) rk[i] = 0;
    __syncthreads();

    const unsigned* pg = prefix + (size_t)(half * HIST_G + g) * HWORDS;
    const int chunk = DIV_UP(E, HIST_G);
    const int beg = g * chunk;
    const int end = min(beg + chunk, E);

    auto do_edge = [&](int d, int s) {
        int r = d - lo;
        if ((unsigned)r < HALF_BINS) {
            int sh = (r & 1) << 4;
            unsigned old = atomicAdd(&rk[r >> 1], 1u << sh);
            unsigned rank = (old >> sh) & 0xFFFFu;
            unsigned pref = (pg[r >> 1] >> sh) & 0xFFFFu;
            int pos = row_off[d] + (int)pref + (int)rank;
            csr_src[pos] = s;
        }
    };

    if ((beg & 3) == 0) {
        for (int base = beg + tid * 4; base < end; base += 256 * 4) {
            if (base + 3 < end) {
                int4 d4 = *reinterpret_cast<const int4*>(dst + base);
                int4 s4 = *reinterpret_cast<const int4*>(src + base);
                do_edge(d4.x, s4.x); do_edge(d4.y, s4.y);
                do_edge(d4.z, s4.z); do_edge(d4.w, s4.w);
            } else {
                for (int k = base; k < end; ++k) do_edge(dst[k], src[k]);
            }
        }
    } else {
        for (int k = beg + tid; k < end; k += 256) do_edge(dst[k], src[k]);
    }
}

// Gather: wave per node. Half-wave (32 lanes) x float4 = one 512B row per load;
// halves take even/odd edges; unroll 4 -> 8 rows in flight per wave.
// layer1 (HAS_SCALE): out[v][:] = sum_{u in N(v)+v} feat[u][:]*scale[u]
// layer2 (HAS_OUT):   out[v][:] = oscale[v]*(sum feat[u][:]) + bias[:]
template <bool HAS_SCALE, bool HAS_OUT>
__global__ __launch_bounds__(256) void k_gather(
    const float* __restrict__ feat, const int* __restrict__ row_off,
    const int* __restrict__ cnt, const int* __restrict__ csr_src,
    const float* __restrict__ scale, const float* __restrict__ oscale,
    const float* __restrict__ bias, float* __restrict__ outv, int n) {
    const int node = blockIdx.x * 4 + (threadIdx.x >> 6);
    const int lane = threadIdx.x & 63;
    if (node >= n) return;
    const int h = lane >> 5, c4 = lane & 31;
    const float4* f = reinterpret_cast<const float4*>(feat);  // row stride 32

    float4 acc = make_float4(0.f, 0.f, 0.f, 0.f);
    const int b = row_off[node];
    const int e2 = b + cnt[node];
    int k = b + h;
    for (; k + 6 < e2; k += 8) {
        int s0 = csr_src[k],     s1 = csr_src[k + 2];
        int s2 = csr_src[k + 4], s3 = csr_src[k + 6];
        float4 v0 = f[(size_t)s0 * 32 + c4];
        float4 v1 = f[(size_t)s1 * 32 + c4];
        float4 v2 = f[(size_t)s2 * 32 + c4];
        float4 v3 = f[(size_t)s3 * 32 + c4];
        float c0 = HAS_SCALE ? scale[s0] : 1.f;
        float c1 = HAS_SCALE ? scale[s1] : 1.f;
        float c2 = HAS_SCALE ? scale[s2] : 1.f;
        float c3 = HAS_SCALE ? scale[s3] : 1.f;
        acc.x += v0.x * c0 + v1.x * c1 + v2.x * c2 + v3.x * c3;
        acc.y += v0.y * c0 + v1.y * c1 + v2.y * c2 + v3.y * c3;
        acc.z += v0.z * c0 + v1.z * c1 + v2.z * c2 + v3.z * c3;
        acc.w += v0.w * c0 + v1.w * c1 + v2.w * c2 + v3.w * c3;
    }
    for (; k < e2; k += 2) {
        int s = csr_src[k];
        float4 v = f[(size_t)s * 32 + c4];
        float c = HAS_SCALE ? scale[s] : 1.f;
        acc.x += v.x * c; acc.y += v.y * c; acc.z += v.z * c; acc.w += v.w * c;
    }
    if (h == 0) {  // self loop
        float4 v = f[(size_t)node * 32 + c4];
        float c = HAS_SCALE ? scale[node] : 1.f;
        acc.x += v.x * c; acc.y += v.y * c; acc.z += v.z * c; acc.w += v.w * c;
    }
    acc.x += __shfl_xor(acc.x, 32);
    acc.y += __shfl_xor(acc.y, 32);
    acc.z += __shfl_xor(acc.z, 32);
    acc.w += __shfl_xor(acc.w, 32);
    if (h == 0) {
        if (HAS_OUT) {
            float os = oscale[node];
            float4 bb = reinterpret_cast<const float4*>(bias)[c4];
            acc.x = acc.x * os + bb.x;
            acc.y = acc.y * os + bb.y;
            acc.z = acc.z * os + bb.z;
            acc.w = acc.w * os + bb.w;
        }
        reinterpret_cast<float4*>(outv)[(size_t)node * 32 + c4] = acc;
    }
}

// Pack both W's fp32 -> hi/lo bf16 in MFMA-B fragment order (one dispatch).
// idx = ((nt*KT + kt)*64 + lane)*8 + j ; k = kt*32 + (lane>>4)*8 + j ; col = nt*16 + (lane&15)
__device__ __forceinline__ void pack_one(const float* __restrict__ W, short* __restrict__ hi,
                                         short* __restrict__ lo, int idx, int KT, int N) {
    int j = idx & 7;
    int l = (idx >> 3) & 63;
    int rest = idx >> 9;
    int kt = rest % KT;
    int nt = rest / KT;
    int k = kt * 32 + ((l >> 4) << 3) + j;
    int col = nt * 16 + (l & 15);
    float w = W[(size_t)k * N + col];
    unsigned u = __builtin_bit_cast(unsigned, w);
    hi[idx] = (short)(u >> 16);
    float hif = __builtin_bit_cast(float, u & 0xFFFF0000u);
    lo[idx] = (short)(__builtin_bit_cast(unsigned, w - hif) >> 16);
}

__global__ void k_pack_both(const float* __restrict__ W1, const float* __restrict__ W2,
                            short* __restrict__ h1, short* __restrict__ l1,
                            short* __restrict__ h2, short* __restrict__ l2) {
    int idx = blockIdx.x * blockDim.x + threadIdx.x;
    const int T1 = IN_DIM * HID_DIM;
    const int T2 = HID_DIM * OUT_DIM;
    if (idx < T1) pack_one(W1, h1, l1, idx, IN_DIM / 32, HID_DIM);
    else if (idx < T1 + T2) pack_one(W2, h2, l2, idx - T1, HID_DIM / 32, OUT_DIM);
}

// C[M x Nc] = epi( (rs_in ⊙ A[M x K]) @ W ), split-bf16 MFMA (hi*hi + lo*hi + hi*lo).
// Block: 256 thr = 4 waves; wave: 16 rows x 128 cols (8 col-tiles of 16x16x32).
template <int KT, bool HAS_RSIN, bool HAS_BIAS, bool RELU, bool HAS_RSOUT>
__global__ __launch_bounds__(256) void k_gemm_mfma(
    const float* __restrict__ A, const short* __restrict__ Bp_hi,
    const short* __restrict__ Bp_lo, const float* __restrict__ bias,
    const float* __restrict__ rs_in, const float* __restrict__ rs_out,
    float* __restrict__ C, int M, int Nc) {
    const int K = KT * 32;
    const int lane = threadIdx.x & 63;
    const int wave = threadIdx.x >> 6;
    const int row0 = blockIdx.y * 64 + wave * 16;
    const int colt0 = blockIdx.x * 8;

    int arow = row0 + (lane & 15);
    int ar = arow < M ? arow : M - 1;
    const int koff = (lane >> 4) << 3;
    const float rs = HAS_RSIN ? rs_in[ar] : 1.0f;

    f32x4 acc[8];
#pragma unroll
    for (int t = 0; t < 8; ++t) acc[t] = (f32x4){0.f, 0.f, 0.f, 0.f};

    const bf16x8* bh = reinterpret_cast<const bf16x8*>(Bp_hi);
    const bf16x8* bl = reinterpret_cast<const bf16x8*>(Bp_lo);

#pragma unroll
    for (int kt = 0; kt < KT; ++kt) {
        const float* ap = A + (size_t)ar * K + kt * 32 + koff;
        float av[8];
        *reinterpret_cast<float4*>(&av[0]) = *reinterpret_cast<const float4*>(ap);
        *reinterpret_cast<float4*>(&av[4]) = *reinterpret_cast<const float4*>(ap + 4);
        bf16x8 a_hi, a_lo;
#pragma unroll
        for (int j = 0; j < 8; ++j) {
            float a = av[j] * rs;
            unsigned u = __builtin_bit_cast(unsigned, a);
            a_hi[j] = (short)(u >> 16);
            float hif = __builtin_bit_cast(float, u & 0xFFFF0000u);
            a_lo[j] = (short)(__builtin_bit_cast(unsigned, a - hif) >> 16);
        }
#pragma unroll
        for (int ct = 0; ct < 8; ++ct) {
            int bidx = (colt0 + ct) * KT + kt;
            bf16x8 bhv = bh[bidx * 64 + lane];
            bf16x8 blv = bl[bidx * 64 + lane];
            acc[ct] = __builtin_amdgcn_mfma_f32_16x16x32_bf16(a_hi, bhv, acc[ct], 0, 0, 0);
            acc[ct] = __builtin_amdgcn_mfma_f32_16x16x32_bf16(a_lo, bhv, acc[ct], 0, 0, 0);
            acc[ct] = __builtin_amdgcn_mfma_f32_16x16x32_bf16(a_hi, blv, acc[ct], 0, 0, 0);
        }
    }

    const int crow0 = row0 + ((lane >> 4) << 2);
    float rso[4];
#pragma unroll
    for (int j = 0; j < 4; ++j)
        rso[j] = HAS_RSOUT ? ((crow0 + j < M) ? rs_out[crow0 + j] : 0.f) : 1.0f;

#pragma unroll
    for (int ct = 0; ct < 8; ++ct) {
        int col = (colt0 + ct) * 16 + (lane & 15);
        float bv = HAS_BIAS ? bias[col] : 0.f;
#pragma unroll
        for (int j = 0; j < 4; ++j) {
            int row = crow0 + j;
            if (row >= M) continue;
            float v = acc[ct][j] + bv;
            if (RELU) v = fmaxf(v, 0.f);
            v *= rso[j];
            C[(size_t)row * Nc + col] = v;
        }
    }
}

extern "C" void kernel_launch(void* const* d_in, const int* in_sizes, int n_in,
                              void* d_out, int out_size, void* d_ws, size_t ws_size,
                              hipStream_t stream) {
    const float* x  = (const float*)d_in[0];
    const int*   ei = (const int*)d_in[1];
    const float* W1 = (const float*)d_in[2];
    const float* b1 = (const float*)d_in[3];
    const float* W2 = (const float*)d_in[4];
    const float* b2 = (const float*)d_in[5];
    float* out = (float*)d_out;

    const int N = in_sizes[0] / IN_DIM;
    const int E = in_sizes[1] / 2;
    const int* src = ei;
    const int* dst = ei + E;

    char* ws = (char*)d_ws;
    size_t off = 0;
    auto alloc = [&](size_t bytes) {
        void* p = ws + off;
        off += (bytes + 255) & ~(size_t)255;
        return p;
    };
    int*   cnt_dst   = (int*)alloc((size_t)N * sizeof(int));
    float* out_isqrt = (float*)alloc((size_t)N * sizeof(float));
    float* in_isqrt  = (float*)alloc((size_t)N * sizeof(float));
    int*   row_off   = (int*)alloc((size_t)N * sizeof(int));
    int*   scan_loc  = (int*)alloc((size_t)N * sizeof(int));
    int*   chunk_sum = (int*)alloc(64 * sizeof(int));
    int*   csr_src   = (int*)alloc((size_t)E * sizeof(int));
    short* W1p_hi    = (short*)alloc((size_t)IN_DIM * HID_DIM * sizeof(short));
    short* W1p_lo    = (short*)alloc((size_t)IN_DIM * HID_DIM * sizeof(short));
    short* W2p_hi    = (short*)alloc((size_t)HID_DIM * OUT_DIM * sizeof(short));
    short* W2p_lo    = (short*)alloc((size_t)HID_DIM * OUT_DIM * sizeof(short));
    float* m1 = (float*)alloc((size_t)N * IN_DIM * sizeof(float));
    float* h1 = (float*)alloc((size_t)N * HID_DIM * sizeof(float));
    float* t2 = (float*)alloc((size_t)N * OUT_DIM * sizeof(float));

    // Overlays (stream-ordered lifetimes):
    //   partials (13.1 MB) on m1  — dead before k_gather writes m1.
    //   prefix   (6.6 MB)  on h1  — dead before k_gemm_mfma writes h1.
    unsigned* partials = (unsigned*)m1;
    unsigned* prefix   = (unsigned*)h1;

    const int thr = 256;
    const int nchunks = DIV_UP(N, 1024);  // 49

    // degrees + normalizers + CSR (no global atomics anywhere)
    k_hist<<<dim3(HIST_G, 4), 256, 0, stream>>>(ei, E, partials);
    k_reduce_scan<<<nchunks, 256, 0, stream>>>(partials, cnt_dst, out_isqrt, in_isqrt,
                                               scan_loc, chunk_sum, prefix, N);
    k_scan_chunks<<<1, 64, 0, stream>>>(chunk_sum, nchunks);
    k_scan_apply<<<DIV_UP(N, 4 * thr), thr, 0, stream>>>(scan_loc, chunk_sum, row_off, N);
    k_fill_rank<<<dim3(HIST_G, 2), 256, 0, stream>>>(src, dst, row_off, prefix, csr_src, E);

    // weight packing (fragment-ordered bf16 hi/lo), one dispatch
    k_pack_both<<<DIV_UP(IN_DIM * HID_DIM + HID_DIM * OUT_DIM, thr), thr, 0, stream>>>(
        W1, W2, W1p_hi, W1p_lo, W2p_hi, W2p_lo);

    // layer 1: m1 = (A+I)(out_isqrt ⊙ x); h1 = relu((in_isqrt ⊙ m1)@W1 + b1)
    k_gather<true, false><<<DIV_UP(N, 4), 256, 0, stream>>>(
        x, row_off, cnt_dst, csr_src, out_isqrt, nullptr, nullptr, m1, N);
    k_gemm_mfma<IN_DIM / 32, true, true, true, false>
        <<<dim3(HID_DIM / 128, DIV_UP(N, 64)), 256, 0, stream>>>(
            m1, W1p_hi, W1p_lo, b1, in_isqrt, nullptr, h1, N, HID_DIM);

    // layer 2: t2 = (h1@W2) ⊙ out_isqrt; out = in_isqrt ⊙ ((A+I) t2) + b2
    k_gemm_mfma<HID_DIM / 32, false, false, false, true>
        <<<dim3(OUT_DIM / 128, DIV_UP(N, 64)), 256, 0, stream>>>(
            h1, W2p_hi, W2p_lo, nullptr, nullptr, out_isqrt, t2, N, OUT_DIM);
    k_gather<false, true><<<DIV_UP(N, 4), 256, 0, stream>>>(
        t2, row_off, cnt_dst, csr_src, nullptr, in_isqrt, b2, out, N);
}

// Round 8
// 277.161 us; speedup vs baseline: 2.7736x; 1.1365x over previous
//
#include <hip/hip_runtime.h>
#include <math.h>

// GCN 2-layer: out = A_norm @ relu(A_norm @ x @ W1 + b1) @ W2 + b2
// A_norm = D_dst^{-1/2} (A + I) D_src^{-1/2}
// Structure:
//   - Degree histograms via LDS privatization (no global atomics).
//   - Fused reduce: partial sums -> cnt_dst/isqrts/local scan + per-histblock
//     exclusive prefix (for atomic-free CSR fill).
//   - k_fill_rank: CSR fill with LDS-only ranking (pos = row_off + prefix + rank).
//   - Aggregation gathers run on BF16 feature rows (256B vs 512B): round-6
//     profile showed gathers bound by L2-miss line count (189MB fetch @3.7TB/s).
//     Per-src scales are folded into the bf16 conversion, so gathers are pure
//     row sums (no per-edge scale load). Accumulation stays fp32.
//   - GEMMs: split-bf16 MFMA (Dekker hi/lo, 3 products), W pre-packed; GEMM2
//     emits bf16 (rowscale_out applied pre-round).
// (Round-7 submission was not measured: GPUAcquisitionTimeout. Resubmitting.)

constexpr int IN_DIM  = 128;
constexpr int HID_DIM = 256;
constexpr int OUT_DIM = 128;

constexpr int HALF_BINS = 25600;          // node-range half (25600*2 >= N), % 1024 == 0
constexpr int HWORDS    = HALF_BINS / 2;  // packed ushort words
constexpr int HIST_G    = 64;             // blocks per (array, half)

#define DIV_UP(a, b) (((a) + (b) - 1) / (b))

typedef __attribute__((ext_vector_type(8))) short bf16x8;
typedef __attribute__((ext_vector_type(4))) float f32x4;

__device__ __forceinline__ unsigned short f2bf_rtn(float v) {
    unsigned u = __builtin_bit_cast(unsigned, v);
    u += 0x7FFFu + ((u >> 16) & 1u);
    return (unsigned short)(u >> 16);
}
__device__ __forceinline__ unsigned pack2bf(float lo, float hi) {
    return (unsigned)f2bf_rtn(lo) | ((unsigned)f2bf_rtn(hi) << 16);
}

// ---- privatized degree histogram: grid (HIST_G, 4); y = half*2 + arr ----
__global__ __launch_bounds__(256) void k_hist(const int* __restrict__ ei, int E,
                                              unsigned* __restrict__ partials) {
    __shared__ unsigned h32[HWORDS];  // 51200 B, packed 2x ushort
    const int tid = threadIdx.x;
    const int g = blockIdx.x;
    const int arr = blockIdx.y & 1, half = blockIdx.y >> 1;
    const int lo = half * HALF_BINS;
    const int* edges = ei + (size_t)arr * E;

    for (int i = tid; i < HWORDS; i += 256) h32[i] = 0;
    __syncthreads();

    const int chunk = DIV_UP(E, HIST_G);
    const int beg = g * chunk;
    const int end = min(beg + chunk, E);
    if ((beg & 3) == 0) {
        for (int base = beg + tid * 4; base < end; base += 256 * 4) {
            if (base + 3 < end) {
                int4 v = *reinterpret_cast<const int4*>(edges + base);
                int r;
                r = v.x - lo; if ((unsigned)r < HALF_BINS) atomicAdd(&h32[r >> 1], 1u << ((r & 1) << 4));
                r = v.y - lo; if ((unsigned)r < HALF_BINS) atomicAdd(&h32[r >> 1], 1u << ((r & 1) << 4));
                r = v.z - lo; if ((unsigned)r < HALF_BINS) atomicAdd(&h32[r >> 1], 1u << ((r & 1) << 4));
                r = v.w - lo; if ((unsigned)r < HALF_BINS) atomicAdd(&h32[r >> 1], 1u << ((r & 1) << 4));
            } else {
                for (int k = base; k < end; ++k) {
                    int r = edges[k] - lo;
                    if ((unsigned)r < HALF_BINS) atomicAdd(&h32[r >> 1], 1u << ((r & 1) << 4));
                }
            }
        }
    } else {
        for (int k = beg + tid; k < end; k += 256) {
            int r = edges[k] - lo;
            if ((unsigned)r < HALF_BINS) atomicAdd(&h32[r >> 1], 1u << ((r & 1) << 4));
        }
    }
    __syncthreads();

    unsigned* outp = partials + (size_t)(blockIdx.y * HIST_G + g) * HWORDS;
    for (int i = tid; i < HWORDS; i += 256) outp[i] = h32[i];
}

// ---- fused reduce + normalizers + local scan + per-g dst prefix ----
// Block b: nodes [b*1024,(b+1)*1024). prefix layout: [half][g][HWORDS] packed ushort.
__global__ __launch_bounds__(256) void k_reduce_scan(
    const unsigned* __restrict__ partials,
    int* __restrict__ cnt_dst, float* __restrict__ out_isqrt, float* __restrict__ in_isqrt,
    int* __restrict__ scan_loc, int* __restrict__ chunk_sum,
    unsigned* __restrict__ prefix, int n) {
    __shared__ int wsum[4];
    const int tid = threadIdx.x, lane = tid & 63, wid = tid >> 6;
    const int bnode = blockIdx.x * 1024;
    const int half = (bnode >= HALF_BINS) ? 1 : 0;  // HALF_BINS % 1024 == 0, no straddle
    const int w0 = ((bnode - half * HALF_BINS) >> 1) + tid * 2;

    const unsigned* ps = partials + (size_t)(2 * half + 0) * HIST_G * HWORDS;
    const unsigned* pd = partials + (size_t)(2 * half + 1) * HIST_G * HWORDS;
    unsigned* pgp = prefix + (size_t)half * HIST_G * HWORDS;

    int s0 = 0, s1 = 0, s2 = 0, s3 = 0;
    int d0 = 0, d1 = 0, d2 = 0, d3 = 0;
#pragma unroll 4
    for (int g = 0; g < HIST_G; ++g) {
        unsigned a = ps[(size_t)g * HWORDS + w0];
        unsigned b = ps[(size_t)g * HWORDS + w0 + 1];
        unsigned c = pd[(size_t)g * HWORDS + w0];
        unsigned d = pd[(size_t)g * HWORDS + w0 + 1];
        // exclusive prefix over g (before accumulating this g's counts)
        pgp[(size_t)g * HWORDS + w0]     = (unsigned)(d0 & 0xFFFF) | ((unsigned)(d1 & 0xFFFF) << 16);
        pgp[(size_t)g * HWORDS + w0 + 1] = (unsigned)(d2 & 0xFFFF) | ((unsigned)(d3 & 0xFFFF) << 16);
        s0 += a & 0xFFFF; s1 += a >> 16; s2 += b & 0xFFFF; s3 += b >> 16;
        d0 += c & 0xFFFF; d1 += c >> 16; d2 += d & 0xFFFF; d3 += d >> 16;
    }

    const int n0 = bnode + tid * 4;
    int sc[4] = {s0, s1, s2, s3};
    int dc[4] = {d0, d1, d2, d3};
#pragma unroll
    for (int j = 0; j < 4; ++j) {
        int node = n0 + j;
        if (node < n) {
            cnt_dst[node] = dc[j];
            out_isqrt[node] = rsqrtf((float)(sc[j] + 1));
            in_isqrt[node]  = rsqrtf((float)(dc[j] + 1));
        } else {
            dc[j] = 0;
        }
    }

    // local exclusive scan of dc over the block's 1024 values
    int s = dc[0] + dc[1] + dc[2] + dc[3];
    int x = s;
#pragma unroll
    for (int off = 1; off < 64; off <<= 1) { int t = __shfl_up(x, off); if (lane >= off) x += t; }
    if (lane == 63) wsum[wid] = x;
    __syncthreads();
    int wo = 0;
    for (int w = 0; w < wid; ++w) wo += wsum[w];
    int excl = wo + x - s;
    int run = excl;
#pragma unroll
    for (int j = 0; j < 4; ++j) {
        int node = n0 + j;
        if (node < n) scan_loc[node] = run;
        run += dc[j];
    }
    if (tid == 255) chunk_sum[blockIdx.x] = wo + x;
}

__global__ void k_scan_chunks(int* __restrict__ chunk_sums, int nc) {  // nc <= 64
    int l = threadIdx.x;
    int v = (l < nc) ? chunk_sums[l] : 0;
    int x = v;
#pragma unroll
    for (int off = 1; off < 64; off <<= 1) { int t = __shfl_up(x, off); if (l >= off) x += t; }
    if (l < nc) chunk_sums[l] = x - v;
}

__global__ void k_scan_apply(const int* __restrict__ local, const int* __restrict__ chunk_sums,
                             int* __restrict__ row_off, int n) {
    int i = (blockIdx.x * blockDim.x + threadIdx.x) * 4;
    if (i >= n) return;
    int add = chunk_sums[i >> 10];
    if (i + 3 < n) {
        int4 v = *reinterpret_cast<const int4*>(local + i);
        v.x += add; v.y += add; v.z += add; v.w += add;
        *reinterpret_cast<int4*>(row_off + i) = v;
    } else {
        for (int k = i; k < n; ++k) row_off[k] = local[k] + add;
    }
}

// ---- atomic-free CSR fill: LDS rank + per-g prefix. grid (HIST_G, 2). ----
__global__ __launch_bounds__(256) void k_fill_rank(
    const int* __restrict__ src, const int* __restrict__ dst,
    const int* __restrict__ row_off, const unsigned* __restrict__ prefix,
    int* __restrict__ csr_src, int E) {
    __shared__ unsigned rk[HWORDS];  // 51.2 KB
    const int tid = threadIdx.x;
    const int g = blockIdx.x, half = blockIdx.y;
    const int lo = half * HALF_BINS;
    for (int i = tid; i < HWORDS; i += 256) rk[i] = 0;
    __syncthreads();

    const unsigned* pg = prefix + (size_t)(half * HIST_G + g) * HWORDS;
    const int chunk = DIV_UP(E, HIST_G);
    const int beg = g * chunk;
    const int end = min(beg + chunk, E);

    auto do_edge = [&](int d, int s) {
        int r = d - lo;
        if ((unsigned)r < HALF_BINS) {
            int sh = (r & 1) << 4;
            unsigned old = atomicAdd(&rk[r >> 1], 1u << sh);
            unsigned rank = (old >> sh) & 0xFFFFu;
            unsigned pref = (pg[r >> 1] >> sh) & 0xFFFFu;
            int pos = row_off[d] + (int)pref + (int)rank;
            csr_src[pos] = s;
        }
    };

    if ((beg & 3) == 0) {
        for (int base = beg + tid * 4; base < end; base += 256 * 4) {
            if (base + 3 < end) {
                int4 d4 = *reinterpret_cast<const int4*>(dst + base);
                int4 s4 = *reinterpret_cast<const int4*>(src + base);
                do_edge(d4.x, s4.x); do_edge(d4.y, s4.y);
                do_edge(d4.z, s4.z); do_edge(d4.w, s4.w);
            } else {
                for (int k = base; k < end; ++k) do_edge(dst[k], src[k]);
            }
        }
    } else {
        for (int k = beg + tid; k < end; k += 256) do_edge(dst[k], src[k]);
    }
}

// xb[u][:] = bf16_rtn(oscale[u] * x[u][:]) ; one thread per 8 elems
__global__ __launch_bounds__(256) void k_cvt(const float* __restrict__ x,
                                             const float* __restrict__ oscale,
                                             uint4* __restrict__ xb, int n16) {
    int idx = blockIdx.x * blockDim.x + threadIdx.x;
    if (idx >= n16) return;
    int row = idx >> 4, w = idx & 15;
    float s = oscale[row];
    const float4* xp = reinterpret_cast<const float4*>(x + ((size_t)row << 7) + w * 8);
    float4 a = xp[0], b = xp[1];
    uint4 o;
    o.x = pack2bf(a.x * s, a.y * s);
    o.y = pack2bf(a.z * s, a.w * s);
    o.z = pack2bf(b.x * s, b.y * s);
    o.w = pack2bf(b.z * s, b.w * s);
    xb[idx] = o;
}

__device__ __forceinline__ void acc_bf8(float* acc, uint4 v) {
    acc[0] += __builtin_bit_cast(float, v.x << 16);
    acc[1] += __builtin_bit_cast(float, v.x & 0xFFFF0000u);
    acc[2] += __builtin_bit_cast(float, v.y << 16);
    acc[3] += __builtin_bit_cast(float, v.y & 0xFFFF0000u);
    acc[4] += __builtin_bit_cast(float, v.z << 16);
    acc[5] += __builtin_bit_cast(float, v.z & 0xFFFF0000u);
    acc[6] += __builtin_bit_cast(float, v.w << 16);
    acc[7] += __builtin_bit_cast(float, v.w & 0xFFFF0000u);
}

// bf16 gather: wave per node; quarter-wave (16 lanes x 16B) = one 256B row.
// Quarters take edges k = b+q step 4; unroll 4 -> 16 rows in flight per wave.
// HAS_OUT=false: out[v][:] = sum rows (feat pre-scaled). fp32 accumulate.
// HAS_OUT=true:  out[v][:] = oscale[v]*sum + bias[:].
template <bool HAS_OUT>
__global__ __launch_bounds__(256) void k_gather_bf16(
    const uint4* __restrict__ feat,  // row = 16 x uint4 (128 bf16)
    const int* __restrict__ row_off, const int* __restrict__ cnt,
    const int* __restrict__ csr_src, const float* __restrict__ oscale,
    const float* __restrict__ bias, float* __restrict__ outv, int n) {
    const int node = blockIdx.x * 4 + (threadIdx.x >> 6);
    const int lane = threadIdx.x & 63;
    if (node >= n) return;
    const int q = lane >> 4, c16 = lane & 15;

    float acc[8] = {};
    const int b = row_off[node];
    const int e2 = b + cnt[node];
    int k = b + q;
    for (; k + 12 < e2; k += 16) {
        int s0 = csr_src[k], s1 = csr_src[k + 4], s2 = csr_src[k + 8], s3 = csr_src[k + 12];
        uint4 v0 = feat[((size_t)s0 << 4) + c16];
        uint4 v1 = feat[((size_t)s1 << 4) + c16];
        uint4 v2 = feat[((size_t)s2 << 4) + c16];
        uint4 v3 = feat[((size_t)s3 << 4) + c16];
        acc_bf8(acc, v0); acc_bf8(acc, v1); acc_bf8(acc, v2); acc_bf8(acc, v3);
    }
    for (; k < e2; k += 4) {
        int s = csr_src[k];
        acc_bf8(acc, feat[((size_t)s << 4) + c16]);
    }
    if (q == 0) acc_bf8(acc, feat[((size_t)node << 4) + c16]);  // self loop

#pragma unroll
    for (int j = 0; j < 8; ++j) {
        acc[j] += __shfl_xor(acc[j], 16);
        acc[j] += __shfl_xor(acc[j], 32);
    }
    if (q == 0) {
        if (HAS_OUT) {
            float os = oscale[node];
            const float4* bb = reinterpret_cast<const float4*>(bias) + c16 * 2;
            float4 b0 = bb[0], b1 = bb[1];
            acc[0] = acc[0] * os + b0.x; acc[1] = acc[1] * os + b0.y;
            acc[2] = acc[2] * os + b0.z; acc[3] = acc[3] * os + b0.w;
            acc[4] = acc[4] * os + b1.x; acc[5] = acc[5] * os + b1.y;
            acc[6] = acc[6] * os + b1.z; acc[7] = acc[7] * os + b1.w;
        }
        float4* op = reinterpret_cast<float4*>(outv + ((size_t)node << 7) + c16 * 8);
        op[0] = make_float4(acc[0], acc[1], acc[2], acc[3]);
        op[1] = make_float4(acc[4], acc[5], acc[6], acc[7]);
    }
}

// Pack both W's fp32 -> hi/lo bf16 in MFMA-B fragment order (one dispatch).
// idx = ((nt*KT + kt)*64 + lane)*8 + j ; k = kt*32 + (lane>>4)*8 + j ; col = nt*16 + (lane&15)
__device__ __forceinline__ void pack_one(const float* __restrict__ W, short* __restrict__ hi,
                                         short* __restrict__ lo, int idx, int KT, int N) {
    int j = idx & 7;
    int l = (idx >> 3) & 63;
    int rest = idx >> 9;
    int kt = rest % KT;
    int nt = rest / KT;
    int k = kt * 32 + ((l >> 4) << 3) + j;
    int col = nt * 16 + (l & 15);
    float w = W[(size_t)k * N + col];
    unsigned u = __builtin_bit_cast(unsigned, w);
    hi[idx] = (short)(u >> 16);
    float hif = __builtin_bit_cast(float, u & 0xFFFF0000u);
    lo[idx] = (short)(__builtin_bit_cast(unsigned, w - hif) >> 16);
}

__global__ void k_pack_both(const float* __restrict__ W1, const float* __restrict__ W2,
                            short* __restrict__ h1, short* __restrict__ l1,
                            short* __restrict__ h2, short* __restrict__ l2) {
    int idx = blockIdx.x * blockDim.x + threadIdx.x;
    const int T1 = IN_DIM * HID_DIM;
    const int T2 = HID_DIM * OUT_DIM;
    if (idx < T1) pack_one(W1, h1, l1, idx, IN_DIM / 32, HID_DIM);
    else if (idx < T1 + T2) pack_one(W2, h2, l2, idx - T1, HID_DIM / 32, OUT_DIM);
}

// C[M x Nc] = epi( (rs_in ⊙ A[M x K]) @ W ), split-bf16 MFMA (hi*hi + lo*hi + hi*lo).
// Block: 256 thr = 4 waves; wave: 16 rows x 128 cols (8 col-tiles of 16x16x32).
// OUT_BF16: store rtn-rounded bf16 (C treated as ushort*).
template <int KT, bool HAS_RSIN, bool HAS_BIAS, bool RELU, bool HAS_RSOUT, bool OUT_BF16>
__global__ __launch_bounds__(256) void k_gemm_mfma(
    const float* __restrict__ A, const short* __restrict__ Bp_hi,
    const short* __restrict__ Bp_lo, const float* __restrict__ bias,
    const float* __restrict__ rs_in, const float* __restrict__ rs_out,
    void* __restrict__ Cv, int M, int Nc) {
    const int K = KT * 32;
    const int lane = threadIdx.x & 63;
    const int wave = threadIdx.x >> 6;
    const int row0 = blockIdx.y * 64 + wave * 16;
    const int colt0 = blockIdx.x * 8;

    int arow = row0 + (lane & 15);
    int ar = arow < M ? arow : M - 1;
    const int koff = (lane >> 4) << 3;
    const float rs = HAS_RSIN ? rs_in[ar] : 1.0f;

    f32x4 acc[8];
#pragma unroll
    for (int t = 0; t < 8; ++t) acc[t] = (f32x4){0.f, 0.f, 0.f, 0.f};

    const bf16x8* bh = reinterpret_cast<const bf16x8*>(Bp_hi);
    const bf16x8* bl = reinterpret_cast<const bf16x8*>(Bp_lo);

#pragma unroll
    for (int kt = 0; kt < KT; ++kt) {
        const float* ap = A + (size_t)ar * K + kt * 32 + koff;
        float av[8];
        *reinterpret_cast<float4*>(&av[0]) = *reinterpret_cast<const float4*>(ap);
        *reinterpret_cast<float4*>(&av[4]) = *reinterpret_cast<const float4*>(ap + 4);
        bf16x8 a_hi, a_lo;
#pragma unroll
        for (int j = 0; j < 8; ++j) {
            float a = av[j] * rs;
            unsigned u = __builtin_bit_cast(unsigned, a);
            a_hi[j] = (short)(u >> 16);
            float hif = __builtin_bit_cast(float, u & 0xFFFF0000u);
            a_lo[j] = (short)(__builtin_bit_cast(unsigned, a - hif) >> 16);
        }
#pragma unroll
        for (int ct = 0; ct < 8; ++ct) {
            int bidx = (colt0 + ct) * KT + kt;
            bf16x8 bhv = bh[bidx * 64 + lane];
            bf16x8 blv = bl[bidx * 64 + lane];
            acc[ct] = __builtin_amdgcn_mfma_f32_16x16x32_bf16(a_hi, bhv, acc[ct], 0, 0, 0);
            acc[ct] = __builtin_amdgcn_mfma_f32_16x16x32_bf16(a_lo, bhv, acc[ct], 0, 0, 0);
            acc[ct] = __builtin_amdgcn_mfma_f32_16x16x32_bf16(a_hi, blv, acc[ct], 0, 0, 0);
        }
    }

    const int crow0 = row0 + ((lane >> 4) << 2);
    float rso[4];
#pragma unroll
    for (int j = 0; j < 4; ++j)
        rso[j] = HAS_RSOUT ? ((crow0 + j < M) ? rs_out[crow0 + j] : 0.f) : 1.0f;

#pragma unroll
    for (int ct = 0; ct < 8; ++ct) {
        int col = (colt0 + ct) * 16 + (lane & 15);
        float bv = HAS_BIAS ? bias[col] : 0.f;
#pragma unroll
        for (int j = 0; j < 4; ++j) {
            int row = crow0 + j;
            if (row >= M) continue;
            float v = acc[ct][j] + bv;
            if (RELU) v = fmaxf(v, 0.f);
            v *= rso[j];
            if (OUT_BF16)
                ((unsigned short*)Cv)[(size_t)row * Nc + col] = f2bf_rtn(v);
            else
                ((float*)Cv)[(size_t)row * Nc + col] = v;
        }
    }
}

extern "C" void kernel_launch(void* const* d_in, const int* in_sizes, int n_in,
                              void* d_out, int out_size, void* d_ws, size_t ws_size,
                              hipStream_t stream) {
    const float* x  = (const float*)d_in[0];
    const int*   ei = (const int*)d_in[1];
    const float* W1 = (const float*)d_in[2];
    const float* b1 = (const float*)d_in[3];
    const float* W2 = (const float*)d_in[4];
    const float* b2 = (const float*)d_in[5];
    float* out = (float*)d_out;

    const int N = in_sizes[0] / IN_DIM;
    const int E = in_sizes[1] / 2;
    const int* src = ei;
    const int* dst = ei + E;

    char* ws = (char*)d_ws;
    size_t off = 0;
    auto alloc = [&](size_t bytes) {
        void* p = ws + off;
        off += (bytes + 255) & ~(size_t)255;
        return p;
    };
    int*   cnt_dst   = (int*)alloc((size_t)N * sizeof(int));
    float* out_isqrt = (float*)alloc((size_t)N * sizeof(float));
    float* in_isqrt  = (float*)alloc((size_t)N * sizeof(float));
    int*   row_off   = (int*)alloc((size_t)N * sizeof(int));
    int*   scan_loc  = (int*)alloc((size_t)N * sizeof(int));
    int*   chunk_sum = (int*)alloc(64 * sizeof(int));
    int*   csr_src   = (int*)alloc((size_t)E * sizeof(int));
    short* W1p_hi    = (short*)alloc((size_t)IN_DIM * HID_DIM * sizeof(short));
    short* W1p_lo    = (short*)alloc((size_t)IN_DIM * HID_DIM * sizeof(short));
    short* W2p_hi    = (short*)alloc((size_t)HID_DIM * OUT_DIM * sizeof(short));
    short* W2p_lo    = (short*)alloc((size_t)HID_DIM * OUT_DIM * sizeof(short));
    float* m1 = (float*)alloc((size_t)N * IN_DIM * sizeof(float));    // 25.6 MB
    float* h1 = (float*)alloc((size_t)N * HID_DIM * sizeof(float));   // 51.2 MB
    uint4* xb  = (uint4*)alloc((size_t)N * IN_DIM * 2);               // 12.8 MB bf16
    unsigned short* t2b = (unsigned short*)alloc((size_t)N * OUT_DIM * 2);  // 12.8 MB bf16

    // Overlays (stream-ordered lifetimes):
    //   partials (13.1 MB) on m1  — dead before k_gather_bf16 writes m1.
    //   prefix   (6.6 MB)  on h1  — dead before k_gemm_mfma writes h1.
    unsigned* partials = (unsigned*)m1;
    unsigned* prefix   = (unsigned*)h1;

    const int thr = 256;
    const int nchunks = DIV_UP(N, 1024);  // 49

    // degrees + normalizers + CSR (no global atomics anywhere)
    k_hist<<<dim3(HIST_G, 4), 256, 0, stream>>>(ei, E, partials);
    k_reduce_scan<<<nchunks, 256, 0, stream>>>(partials, cnt_dst, out_isqrt, in_isqrt,
                                               scan_loc, chunk_sum, prefix, N);
    k_scan_chunks<<<1, 64, 0, stream>>>(chunk_sum, nchunks);
    k_scan_apply<<<DIV_UP(N, 4 * thr), thr, 0, stream>>>(scan_loc, chunk_sum, row_off, N);
    k_fill_rank<<<dim3(HIST_G, 2), 256, 0, stream>>>(src, dst, row_off, prefix, csr_src, E);

    // weight packing + feature conversion (xb = bf16(out_isqrt ⊙ x))
    k_pack_both<<<DIV_UP(IN_DIM * HID_DIM + HID_DIM * OUT_DIM, thr), thr, 0, stream>>>(
        W1, W2, W1p_hi, W1p_lo, W2p_hi, W2p_lo);
    k_cvt<<<DIV_UP(N * 16, thr), thr, 0, stream>>>(x, out_isqrt, xb, N * 16);

    // layer 1: m1 = (A+I) xb; h1 = relu((in_isqrt ⊙ m1)@W1 + b1)
    k_gather_bf16<false><<<DIV_UP(N, 4), 256, 0, stream>>>(
        xb, row_off, cnt_dst, csr_src, nullptr, nullptr, m1, N);
    k_gemm_mfma<IN_DIM / 32, true, true, true, false, false>
        <<<dim3(HID_DIM / 128, DIV_UP(N, 64)), 256, 0, stream>>>(
            m1, W1p_hi, W1p_lo, b1, in_isqrt, nullptr, h1, N, HID_DIM);

    // layer 2: t2b = bf16(out_isqrt ⊙ (h1@W2)); out = in_isqrt ⊙ ((A+I) t2b) + b2
    k_gemm_mfma<HID_DIM / 32, false, false, false, true, true>
        <<<dim3(OUT_DIM / 128, DIV_UP(N, 64)), 256, 0, stream>>>(
            h1, W2p_hi, W2p_lo, nullptr, nullptr, out_isqrt, t2b, N, OUT_DIM);
    k_gather_bf16<true><<<DIV_UP(N, 4), 256, 0, stream>>>(
        (const uint4*)t2b, row_off, cnt_dst, csr_src, in_isqrt, b2, out, N);
}

// Round 9
// 267.169 us; speedup vs baseline: 2.8773x; 1.0374x over previous
//
#include <hip/hip_runtime.h>
#include <math.h>

// GCN 2-layer: out = A_norm @ relu(A_norm @ x @ W1 + b1) @ W2 + b2
// A_norm = D_dst^{-1/2} (A + I) D_src^{-1/2}
// Structure:
//   - Degree histograms via LDS privatization (no global atomics).
//   - Fused reduce: partial sums -> cnt_dst/isqrts/local scan + per-histblock
//     exclusive prefix; scan_apply re-scans chunk sums per block (fused).
//   - k_fill_rank: CSR fill with LDS-only ranking (no global atomics).
//   - Gathers on BF16 rows (256B), fp32 accumulate; per-src scale folded into
//     conversion, per-dst scale folded into gather epilogue.
//   - ALL intermediates (m1, h1, t2) are plain bf16: input-side bf16 rounding
//     is attenuated ~W-column-norm (1/sqrt(K)) through each GEMM (measured:
//     round-8 absmax unchanged at 0.00195 with bf16 gather inputs).
//   - GEMMs: bf16 A (exact, no split) x split-bf16 W (hi/lo) = 2 MFMA products;
//     K-loop has no unpack VALU at all.

constexpr int IN_DIM  = 128;
constexpr int HID_DIM = 256;
constexpr int OUT_DIM = 128;

constexpr int HALF_BINS = 25600;          // node-range half (25600*2 >= N), % 1024 == 0
constexpr int HWORDS    = HALF_BINS / 2;  // packed ushort words
constexpr int HIST_G    = 64;             // blocks per (array, half)

#define DIV_UP(a, b) (((a) + (b) - 1) / (b))

typedef __attribute__((ext_vector_type(8))) short bf16x8;
typedef __attribute__((ext_vector_type(4))) float f32x4;

__device__ __forceinline__ unsigned short f2bf_rtn(float v) {
    unsigned u = __builtin_bit_cast(unsigned, v);
    u += 0x7FFFu + ((u >> 16) & 1u);
    return (unsigned short)(u >> 16);
}
__device__ __forceinline__ unsigned pack2bf(float lo, float hi) {
    return (unsigned)f2bf_rtn(lo) | ((unsigned)f2bf_rtn(hi) << 16);
}

// ---- privatized degree histogram: grid (HIST_G, 4); y = half*2 + arr ----
__global__ __launch_bounds__(256) void k_hist(const int* __restrict__ ei, int E,
                                              unsigned* __restrict__ partials) {
    __shared__ unsigned h32[HWORDS];  // 51200 B, packed 2x ushort
    const int tid = threadIdx.x;
    const int g = blockIdx.x;
    const int arr = blockIdx.y & 1, half = blockIdx.y >> 1;
    const int lo = half * HALF_BINS;
    const int* edges = ei + (size_t)arr * E;

    for (int i = tid; i < HWORDS; i += 256) h32[i] = 0;
    __syncthreads();

    const int chunk = DIV_UP(E, HIST_G);
    const int beg = g * chunk;
    const int end = min(beg + chunk, E);
    if ((beg & 3) == 0) {
        for (int base = beg + tid * 4; base < end; base += 256 * 4) {
            if (base + 3 < end) {
                int4 v = *reinterpret_cast<const int4*>(edges + base);
                int r;
                r = v.x - lo; if ((unsigned)r < HALF_BINS) atomicAdd(&h32[r >> 1], 1u << ((r & 1) << 4));
                r = v.y - lo; if ((unsigned)r < HALF_BINS) atomicAdd(&h32[r >> 1], 1u << ((r & 1) << 4));
                r = v.z - lo; if ((unsigned)r < HALF_BINS) atomicAdd(&h32[r >> 1], 1u << ((r & 1) << 4));
                r = v.w - lo; if ((unsigned)r < HALF_BINS) atomicAdd(&h32[r >> 1], 1u << ((r & 1) << 4));
            } else {
                for (int k = base; k < end; ++k) {
                    int r = edges[k] - lo;
                    if ((unsigned)r < HALF_BINS) atomicAdd(&h32[r >> 1], 1u << ((r & 1) << 4));
                }
            }
        }
    } else {
        for (int k = beg + tid; k < end; k += 256) {
            int r = edges[k] - lo;
            if ((unsigned)r < HALF_BINS) atomicAdd(&h32[r >> 1], 1u << ((r & 1) << 4));
        }
    }
    __syncthreads();

    unsigned* outp = partials + (size_t)(blockIdx.y * HIST_G + g) * HWORDS;
    for (int i = tid; i < HWORDS; i += 256) outp[i] = h32[i];
}

// ---- fused reduce + normalizers + local scan + per-g dst prefix ----
__global__ __launch_bounds__(256) void k_reduce_scan(
    const unsigned* __restrict__ partials,
    int* __restrict__ cnt_dst, float* __restrict__ out_isqrt, float* __restrict__ in_isqrt,
    int* __restrict__ scan_loc, int* __restrict__ chunk_sum,
    unsigned* __restrict__ prefix, int n) {
    __shared__ int wsum[4];
    const int tid = threadIdx.x, lane = tid & 63, wid = tid >> 6;
    const int bnode = blockIdx.x * 1024;
    const int half = (bnode >= HALF_BINS) ? 1 : 0;  // HALF_BINS % 1024 == 0, no straddle
    const int w0 = ((bnode - half * HALF_BINS) >> 1) + tid * 2;

    const unsigned* ps = partials + (size_t)(2 * half + 0) * HIST_G * HWORDS;
    const unsigned* pd = partials + (size_t)(2 * half + 1) * HIST_G * HWORDS;
    unsigned* pgp = prefix + (size_t)half * HIST_G * HWORDS;

    int s0 = 0, s1 = 0, s2 = 0, s3 = 0;
    int d0 = 0, d1 = 0, d2 = 0, d3 = 0;
#pragma unroll 4
    for (int g = 0; g < HIST_G; ++g) {
        unsigned a = ps[(size_t)g * HWORDS + w0];
        unsigned b = ps[(size_t)g * HWORDS + w0 + 1];
        unsigned c = pd[(size_t)g * HWORDS + w0];
        unsigned d = pd[(size_t)g * HWORDS + w0 + 1];
        pgp[(size_t)g * HWORDS + w0]     = (unsigned)(d0 & 0xFFFF) | ((unsigned)(d1 & 0xFFFF) << 16);
        pgp[(size_t)g * HWORDS + w0 + 1] = (unsigned)(d2 & 0xFFFF) | ((unsigned)(d3 & 0xFFFF) << 16);
        s0 += a & 0xFFFF; s1 += a >> 16; s2 += b & 0xFFFF; s3 += b >> 16;
        d0 += c & 0xFFFF; d1 += c >> 16; d2 += d & 0xFFFF; d3 += d >> 16;
    }

    const int n0 = bnode + tid * 4;
    int sc[4] = {s0, s1, s2, s3};
    int dc[4] = {d0, d1, d2, d3};
#pragma unroll
    for (int j = 0; j < 4; ++j) {
        int node = n0 + j;
        if (node < n) {
            cnt_dst[node] = dc[j];
            out_isqrt[node] = rsqrtf((float)(sc[j] + 1));
            in_isqrt[node]  = rsqrtf((float)(dc[j] + 1));
        } else {
            dc[j] = 0;
        }
    }

    int s = dc[0] + dc[1] + dc[2] + dc[3];
    int x = s;
#pragma unroll
    for (int off = 1; off < 64; off <<= 1) { int t = __shfl_up(x, off); if (lane >= off) x += t; }
    if (lane == 63) wsum[wid] = x;
    __syncthreads();
    int wo = 0;
    for (int w = 0; w < wid; ++w) wo += wsum[w];
    int excl = wo + x - s;
    int run = excl;
#pragma unroll
    for (int j = 0; j < 4; ++j) {
        int node = n0 + j;
        if (node < n) scan_loc[node] = run;
        run += dc[j];
    }
    if (tid == 255) chunk_sum[blockIdx.x] = wo + x;
}

// scan_apply with fused chunk scan: block b == chunk b; wave 0 scans chunk sums.
__global__ __launch_bounds__(256) void k_scan_apply(
    const int* __restrict__ local, const int* __restrict__ chunk_sum,
    int* __restrict__ row_off, int n, int nc) {
    __shared__ int base_s;
    const int tid = threadIdx.x;
    if (tid < 64) {
        int v = (tid < nc) ? chunk_sum[tid] : 0;
        int x = v;
#pragma unroll
        for (int off = 1; off < 64; off <<= 1) { int t = __shfl_up(x, off); if (tid >= off) x += t; }
        if (tid == blockIdx.x) base_s = x - v;  // exclusive prefix at this chunk
    }
    __syncthreads();
    const int add = base_s;
    int i = blockIdx.x * 1024 + tid * 4;
    if (i >= n) return;
    if (i + 3 < n) {
        int4 v = *reinterpret_cast<const int4*>(local + i);
        v.x += add; v.y += add; v.z += add; v.w += add;
        *reinterpret_cast<int4*>(row_off + i) = v;
    } else {
        for (int k = i; k < n; ++k) row_off[k] = local[k] + add;
    }
}

// ---- atomic-free CSR fill: LDS rank + per-g prefix. grid (HIST_G, 2). ----
__global__ __launch_bounds__(256) void k_fill_rank(
    const int* __restrict__ src, const int* __restrict__ dst,
    const int* __restrict__ row_off, const unsigned* __restrict__ prefix,
    int* __restrict__ csr_src, int E) {
    __shared__ unsigned rk[HWORDS];  // 51.2 KB
    const int tid = threadIdx.x;
    const int g = blockIdx.x, half = blockIdx.y;
    const int lo = half * HALF_BINS;
    for (int i = tid; i < HWORDS; i += 256) rk[i] = 0;
    __syncthreads();

    const unsigned* pg = prefix + (size_t)(half * HIST_G + g) * HWORDS;
    const int chunk = DIV_UP(E, HIST_G);
    const int beg = g * chunk;
    const int end = min(beg + chunk, E);

    auto do_edge = [&](int d, int s) {
        int r = d - lo;
        if ((unsigned)r < HALF_BINS) {
            int sh = (r & 1) << 4;
            unsigned old = atomicAdd(&rk[r >> 1], 1u << sh);
            unsigned rank = (old >> sh) & 0xFFFFu;
            unsigned pref = (pg[r >> 1] >> sh) & 0xFFFFu;
            int pos = row_off[d] + (int)pref + (int)rank;
            csr_src[pos] = s;
        }
    };

    if ((beg & 3) == 0) {
        for (int base = beg + tid * 4; base < end; base += 256 * 4) {
            if (base + 3 < end) {
                int4 d4 = *reinterpret_cast<const int4*>(dst + base);
                int4 s4 = *reinterpret_cast<const int4*>(src + base);
                do_edge(d4.x, s4.x); do_edge(d4.y, s4.y);
                do_edge(d4.z, s4.z); do_edge(d4.w, s4.w);
            } else {
                for (int k = base; k < end; ++k) do_edge(dst[k], src[k]);
            }
        }
    } else {
        for (int k = beg + tid; k < end; k += 256) do_edge(dst[k], src[k]);
    }
}

// xb[u][:] = bf16_rtn(oscale[u] * x[u][:]) ; one thread per 8 elems
__global__ __launch_bounds__(256) void k_cvt(const float* __restrict__ x,
                                             const float* __restrict__ oscale,
                                             uint4* __restrict__ xb, int n16) {
    int idx = blockIdx.x * blockDim.x + threadIdx.x;
    if (idx >= n16) return;
    int row = idx >> 4, w = idx & 15;
    float s = oscale[row];
    const float4* xp = reinterpret_cast<const float4*>(x + ((size_t)row << 7) + w * 8);
    float4 a = xp[0], b = xp[1];
    uint4 o;
    o.x = pack2bf(a.x * s, a.y * s);
    o.y = pack2bf(a.z * s, a.w * s);
    o.z = pack2bf(b.x * s, b.y * s);
    o.w = pack2bf(b.z * s, b.w * s);
    xb[idx] = o;
}

__device__ __forceinline__ void acc_bf8(float* acc, uint4 v) {
    acc[0] += __builtin_bit_cast(float, v.x << 16);
    acc[1] += __builtin_bit_cast(float, v.x & 0xFFFF0000u);
    acc[2] += __builtin_bit_cast(float, v.y << 16);
    acc[3] += __builtin_bit_cast(float, v.y & 0xFFFF0000u);
    acc[4] += __builtin_bit_cast(float, v.z << 16);
    acc[5] += __builtin_bit_cast(float, v.z & 0xFFFF0000u);
    acc[6] += __builtin_bit_cast(float, v.w << 16);
    acc[7] += __builtin_bit_cast(float, v.w & 0xFFFF0000u);
}

// bf16 gather: wave per node; quarter-wave (16 lanes x 16B) = one 256B row.
// out[v][:] = oscale[v]*(Σ_{u in N(v)+v} feat[u][:]) (+ bias). fp32 accumulate.
// OUT_BF16: emit packed bf16 row; else fp32.
template <bool HAS_BIAS, bool OUT_BF16>
__global__ __launch_bounds__(256) void k_gather_bf16(
    const uint4* __restrict__ feat,  // row = 16 x uint4 (128 bf16)
    const int* __restrict__ row_off, const int* __restrict__ cnt,
    const int* __restrict__ csr_src, const float* __restrict__ oscale,
    const float* __restrict__ bias, void* __restrict__ outv, int n) {
    const int node = blockIdx.x * 4 + (threadIdx.x >> 6);
    const int lane = threadIdx.x & 63;
    if (node >= n) return;
    const int q = lane >> 4, c16 = lane & 15;

    float acc[8] = {};
    const int b = row_off[node];
    const int e2 = b + cnt[node];
    int k = b + q;
    for (; k + 12 < e2; k += 16) {
        int s0 = csr_src[k], s1 = csr_src[k + 4], s2 = csr_src[k + 8], s3 = csr_src[k + 12];
        uint4 v0 = feat[((size_t)s0 << 4) + c16];
        uint4 v1 = feat[((size_t)s1 << 4) + c16];
        uint4 v2 = feat[((size_t)s2 << 4) + c16];
        uint4 v3 = feat[((size_t)s3 << 4) + c16];
        acc_bf8(acc, v0); acc_bf8(acc, v1); acc_bf8(acc, v2); acc_bf8(acc, v3);
    }
    for (; k < e2; k += 4) {
        int s = csr_src[k];
        acc_bf8(acc, feat[((size_t)s << 4) + c16]);
    }
    if (q == 0) acc_bf8(acc, feat[((size_t)node << 4) + c16]);  // self loop

#pragma unroll
    for (int j = 0; j < 8; ++j) {
        acc[j] += __shfl_xor(acc[j], 16);
        acc[j] += __shfl_xor(acc[j], 32);
    }
    if (q == 0) {
        float os = oscale[node];
        if (HAS_BIAS) {
            const float4* bb = reinterpret_cast<const float4*>(bias) + c16 * 2;
            float4 b0 = bb[0], b1 = bb[1];
            acc[0] = acc[0] * os + b0.x; acc[1] = acc[1] * os + b0.y;
            acc[2] = acc[2] * os + b0.z; acc[3] = acc[3] * os + b0.w;
            acc[4] = acc[4] * os + b1.x; acc[5] = acc[5] * os + b1.y;
            acc[6] = acc[6] * os + b1.z; acc[7] = acc[7] * os + b1.w;
        } else {
#pragma unroll
            for (int j = 0; j < 8; ++j) acc[j] *= os;
        }
        if (OUT_BF16) {
            uint4 o;
            o.x = pack2bf(acc[0], acc[1]);
            o.y = pack2bf(acc[2], acc[3]);
            o.z = pack2bf(acc[4], acc[5]);
            o.w = pack2bf(acc[6], acc[7]);
            reinterpret_cast<uint4*>(outv)[((size_t)node << 4) + c16] = o;
        } else {
            float4* op = reinterpret_cast<float4*>((float*)outv + ((size_t)node << 7) + c16 * 8);
            op[0] = make_float4(acc[0], acc[1], acc[2], acc[3]);
            op[1] = make_float4(acc[4], acc[5], acc[6], acc[7]);
        }
    }
}

// Pack both W's fp32 -> hi/lo bf16 in MFMA-B fragment order (one dispatch).
__device__ __forceinline__ void pack_one(const float* __restrict__ W, short* __restrict__ hi,
                                         short* __restrict__ lo, int idx, int KT, int N) {
    int j = idx & 7;
    int l = (idx >> 3) & 63;
    int rest = idx >> 9;
    int kt = rest % KT;
    int nt = rest / KT;
    int k = kt * 32 + ((l >> 4) << 3) + j;
    int col = nt * 16 + (l & 15);
    float w = W[(size_t)k * N + col];
    unsigned u = __builtin_bit_cast(unsigned, w);
    hi[idx] = (short)(u >> 16);
    float hif = __builtin_bit_cast(float, u & 0xFFFF0000u);
    lo[idx] = (short)(__builtin_bit_cast(unsigned, w - hif) >> 16);
}

__global__ void k_pack_both(const float* __restrict__ W1, const float* __restrict__ W2,
                            short* __restrict__ h1, short* __restrict__ l1,
                            short* __restrict__ h2, short* __restrict__ l2) {
    int idx = blockIdx.x * blockDim.x + threadIdx.x;
    const int T1 = IN_DIM * HID_DIM;
    const int T2 = HID_DIM * OUT_DIM;
    if (idx < T1) pack_one(W1, h1, l1, idx, IN_DIM / 32, HID_DIM);
    else if (idx < T1 + T2) pack_one(W2, h2, l2, idx - T1, HID_DIM / 32, OUT_DIM);
}

// C[M x Nc] = epi( A[M x K](bf16) @ W(split hi/lo) ): 2 MFMAs per (kt,ct),
// no unpack VALU in the K-loop (A is exact bf16).
// Block: 256 thr = 4 waves; wave: 16 rows x 128 cols (8 col-tiles of 16x16x32).
template <int KT, bool HAS_BIAS, bool RELU, bool HAS_RSOUT, bool OUT_BF16>
__global__ __launch_bounds__(256) void k_gemm_bf16(
    const unsigned short* __restrict__ A, const short* __restrict__ Bp_hi,
    const short* __restrict__ Bp_lo, const float* __restrict__ bias,
    const float* __restrict__ rs_out, void* __restrict__ Cv, int M, int Nc) {
    const int K = KT * 32;
    const int lane = threadIdx.x & 63;
    const int wave = threadIdx.x >> 6;
    const int row0 = blockIdx.y * 64 + wave * 16;
    const int colt0 = blockIdx.x * 8;

    int arow = row0 + (lane & 15);
    int ar = arow < M ? arow : M - 1;
    const int koff = (lane >> 4) << 3;

    f32x4 acc[8];
#pragma unroll
    for (int t = 0; t < 8; ++t) acc[t] = (f32x4){0.f, 0.f, 0.f, 0.f};

    const bf16x8* bh = reinterpret_cast<const bf16x8*>(Bp_hi);
    const bf16x8* bl = reinterpret_cast<const bf16x8*>(Bp_lo);

#pragma unroll
    for (int kt = 0; kt < KT; ++kt) {
        bf16x8 a = *reinterpret_cast<const bf16x8*>(A + (size_t)ar * K + kt * 32 + koff);
#pragma unroll
        for (int ct = 0; ct < 8; ++ct) {
            int bidx = (colt0 + ct) * KT + kt;
            bf16x8 bhv = bh[bidx * 64 + lane];
            bf16x8 blv = bl[bidx * 64 + lane];
            acc[ct] = __builtin_amdgcn_mfma_f32_16x16x32_bf16(a, bhv, acc[ct], 0, 0, 0);
            acc[ct] = __builtin_amdgcn_mfma_f32_16x16x32_bf16(a, blv, acc[ct], 0, 0, 0);
        }
    }

    const int crow0 = row0 + ((lane >> 4) << 2);
    float rso[4];
#pragma unroll
    for (int j = 0; j < 4; ++j)
        rso[j] = HAS_RSOUT ? ((crow0 + j < M) ? rs_out[crow0 + j] : 0.f) : 1.0f;

#pragma unroll
    for (int ct = 0; ct < 8; ++ct) {
        int col = (colt0 + ct) * 16 + (lane & 15);
        float bv = HAS_BIAS ? bias[col] : 0.f;
#pragma unroll
        for (int j = 0; j < 4; ++j) {
            int row = crow0 + j;
            if (row >= M) continue;
            float v = acc[ct][j] + bv;
            if (RELU) v = fmaxf(v, 0.f);
            v *= rso[j];
            if (OUT_BF16)
                ((unsigned short*)Cv)[(size_t)row * Nc + col] = f2bf_rtn(v);
            else
                ((float*)Cv)[(size_t)row * Nc + col] = v;
        }
    }
}

extern "C" void kernel_launch(void* const* d_in, const int* in_sizes, int n_in,
                              void* d_out, int out_size, void* d_ws, size_t ws_size,
                              hipStream_t stream) {
    const float* x  = (const float*)d_in[0];
    const int*   ei = (const int*)d_in[1];
    const float* W1 = (const float*)d_in[2];
    const float* b1 = (const float*)d_in[3];
    const float* W2 = (const float*)d_in[4];
    const float* b2 = (const float*)d_in[5];
    float* out = (float*)d_out;

    const int N = in_sizes[0] / IN_DIM;
    const int E = in_sizes[1] / 2;
    const int* src = ei;
    const int* dst = ei + E;

    char* ws = (char*)d_ws;
    size_t off = 0;
    auto alloc = [&](size_t bytes) {
        void* p = ws + off;
        off += (bytes + 255) & ~(size_t)255;
        return p;
    };
    int*   cnt_dst   = (int*)alloc((size_t)N * sizeof(int));
    float* out_isqrt = (float*)alloc((size_t)N * sizeof(float));
    float* in_isqrt  = (float*)alloc((size_t)N * sizeof(float));
    int*   row_off   = (int*)alloc((size_t)N * sizeof(int));
    int*   scan_loc  = (int*)alloc((size_t)N * sizeof(int));
    int*   chunk_sum = (int*)alloc(64 * sizeof(int));
    int*   csr_src   = (int*)alloc((size_t)E * sizeof(int));
    short* W1p_hi    = (short*)alloc((size_t)IN_DIM * HID_DIM * sizeof(short));
    short* W1p_lo    = (short*)alloc((size_t)IN_DIM * HID_DIM * sizeof(short));
    short* W2p_hi    = (short*)alloc((size_t)HID_DIM * OUT_DIM * sizeof(short));
    short* W2p_lo    = (short*)alloc((size_t)HID_DIM * OUT_DIM * sizeof(short));
    uint4* xb  = (uint4*)alloc((size_t)N * IN_DIM * 2);                        // 12.8 MB bf16
    unsigned short* m1b = (unsigned short*)alloc((size_t)N * IN_DIM * 2);      // 12.8 MB bf16
    unsigned short* h1b = (unsigned short*)alloc((size_t)N * HID_DIM * 2);     // 25.6 MB bf16
    unsigned short* t2b = (unsigned short*)alloc((size_t)N * OUT_DIM * 2);     // 12.8 MB bf16

    // Overlays on h1b (25.6 MB), both dead before k_gemm_bf16 writes h1b:
    //   partials 13.1 MB at offset 0; prefix 6.6 MB right after.
    unsigned* partials = (unsigned*)h1b;
    unsigned* prefix   = (unsigned*)((char*)h1b + (size_t)4 * HIST_G * HWORDS * 4);

    const int thr = 256;
    const int nchunks = DIV_UP(N, 1024);  // 49

    // degrees + normalizers + CSR (no global atomics anywhere)
    k_hist<<<dim3(HIST_G, 4), 256, 0, stream>>>(ei, E, partials);
    k_reduce_scan<<<nchunks, 256, 0, stream>>>(partials, cnt_dst, out_isqrt, in_isqrt,
                                               scan_loc, chunk_sum, prefix, N);
    k_scan_apply<<<nchunks, 256, 0, stream>>>(scan_loc, chunk_sum, row_off, N, nchunks);
    k_fill_rank<<<dim3(HIST_G, 2), 256, 0, stream>>>(src, dst, row_off, prefix, csr_src, E);

    // weight packing + feature conversion (xb = bf16(out_isqrt ⊙ x))
    k_pack_both<<<DIV_UP(IN_DIM * HID_DIM + HID_DIM * OUT_DIM, thr), thr, 0, stream>>>(
        W1, W2, W1p_hi, W1p_lo, W2p_hi, W2p_lo);
    k_cvt<<<DIV_UP(N * 16, thr), thr, 0, stream>>>(x, out_isqrt, xb, N * 16);

    // layer 1: m1b = bf16(in_isqrt ⊙ (A+I) xb); h1b = bf16(relu(m1b@W1 + b1))
    k_gather_bf16<false, true><<<DIV_UP(N, 4), 256, 0, stream>>>(
        xb, row_off, cnt_dst, csr_src, in_isqrt, nullptr, m1b, N);
    k_gemm_bf16<IN_DIM / 32, true, true, false, true>
        <<<dim3(HID_DIM / 128, DIV_UP(N, 64)), 256, 0, stream>>>(
            m1b, W1p_hi, W1p_lo, b1, nullptr, h1b, N, HID_DIM);

    // layer 2: t2b = bf16(out_isqrt ⊙ (h1b@W2)); out = in_isqrt ⊙ ((A+I) t2b) + b2
    k_gemm_bf16<HID_DIM / 32, false, false, true, true>
        <<<dim3(OUT_DIM / 128, DIV_UP(N, 64)), 256, 0, stream>>>(
            h1b, W2p_hi, W2p_lo, nullptr, out_isqrt, t2b, N, OUT_DIM);
    k_gather_bf16<true, false><<<DIV_UP(N, 4), 256, 0, stream>>>(
        (const uint4*)t2b, row_off, cnt_dst, csr_src, in_isqrt, b2, out, N);
}